// Round 1
// 1168.017 us; speedup vs baseline: 1.2401x; 1.2401x over previous
//
#include <hip/hip_runtime.h>
#include <cstdint>
#include <cstddef>

// Problem constants (fixed by setup_inputs): B*S=8192, I=4096, O=11008, n_g=64
#define M_DIM 8192
#define N_DIM 11008
#define K_DIM 4096
#define K_TILES 64   // K_DIM / 64
#define NITER   32   // K_TILES / 2

typedef __attribute__((ext_vector_type(8))) __bf16 bf16x8;
typedef __attribute__((ext_vector_type(4))) float f32x4;
typedef __attribute__((ext_vector_type(8))) unsigned short ushort8v;

__device__ __forceinline__ unsigned short bf16rn(float f) {
  unsigned int u = __float_as_uint(f);
  u += 0x7FFFu + ((u >> 16) & 1u);   // round-to-nearest-even
  return (unsigned short)(u >> 16);
}

// ---------------- Pass 1a: x fp32 -> bf16 ----------------
__global__ void cvt_x_kernel(const float* __restrict__ x,
                             unsigned short* __restrict__ xb) {
  const int i = (blockIdx.x * 256 + threadIdx.x) * 8;
  const float4 a = *(const float4*)(x + i);
  const float4 b = *(const float4*)(x + i + 4);
  ushort8v o;
  o[0] = bf16rn(a.x); o[1] = bf16rn(a.y); o[2] = bf16rn(a.z); o[3] = bf16rn(a.w);
  o[4] = bf16rn(b.x); o[5] = bf16rn(b.y); o[6] = bf16rn(b.z); o[7] = bf16rn(b.w);
  *(ushort8v*)(xb + i) = o;
}

// ---------------- Pass 1b: dequantize W -> bf16 [O, I] K-major ----------------
__global__ void dequant_w_kernel(const int* __restrict__ wq,
                                 const float* __restrict__ scales,
                                 const float* __restrict__ zeros,
                                 const float* __restrict__ csc,
                                 unsigned short* __restrict__ wb) {
  const int gid = blockIdx.x * 256 + threadIdx.x;
  const int row = gid >> 9;      // / 512
  const int j4  = gid & 511;     // 4-word position in row
  const int4 q = *(const int4*)(wq + row * 2048 + j4 * 4);
  const int g = j4 >> 3;         // (j4*8)/64
  const float s = scales[row * 64 + g];
  const float z = zeros[row * 64 + g];
  const int col = j4 * 8;
  const float4 c0 = *(const float4*)(csc + col);
  const float4 c1 = *(const float4*)(csc + col + 4);
  ushort8v o;
  o[0] = bf16rn((s * (float)( q.x        & 15) + z) * c0.x);
  o[1] = bf16rn((s * (float)((q.x >> 4)  & 15) + z) * c0.y);
  o[2] = bf16rn((s * (float)( q.y        & 15) + z) * c0.z);
  o[3] = bf16rn((s * (float)((q.y >> 4)  & 15) + z) * c0.w);
  o[4] = bf16rn((s * (float)( q.z        & 15) + z) * c1.x);
  o[5] = bf16rn((s * (float)((q.z >> 4)  & 15) + z) * c1.y);
  o[6] = bf16rn((s * (float)( q.w        & 15) + z) * c1.z);
  o[7] = bf16rn((s * (float)((q.w >> 4)  & 15) + z) * c1.w);
  *(ushort8v*)(wb + row * 4096 + col) = o;
}

// ---------------- Pass 2: bf16 GEMM, 256x256 tile, 8-phase pipelined ----------------
// C[M,N] = A[M,K] * B[N,K]^T + bias.
// 512 threads = 8 waves (2 M x 4 N), each wave owns a 128x64 output sub-tile.
// LDS: 2 buffers x {A,B} x {k-half 0,1} regions of [256 rows][32 k] bf16 = 8 x 16KiB = 128KiB.
// Swizzle: byte ^= ((row>>1)&3)<<4 within a region (uniform bank spread for ds_read_b128).
//   Applied as: linear global_load_lds dest + pre-swizzled global SOURCE lane + swizzled READ.
// Pipeline: 8 phases/iter (2 K-tiles). Per phase: ds_read subtile + 1 half-tile prefetch
//   -> s_barrier -> lgkmcnt(0) -> setprio(1) 16xMFMA setprio(0) -> [vmcnt(6) at ph3/ph7] -> s_barrier.
//   vmcnt never drains to 0 in the main loop (3 half-tiles = 6 loads stay in flight).

__device__ __forceinline__ void gld_lds16(const void* gp, void* lp) {
  __builtin_amdgcn_global_load_lds(
      (__attribute__((address_space(1))) void*)gp,
      (__attribute__((address_space(3))) void*)lp,
      16, 0, 0);
}

#define BARRIER()    asm volatile("s_barrier" ::: "memory")
#define WAIT_LGKM0() asm volatile("s_waitcnt lgkmcnt(0)" ::: "memory")
#define WAIT_VM6()   asm volatile("s_waitcnt vmcnt(6)" ::: "memory")

// region base (ushort units): [buf][mat A=0/B=1][khalf], each 8192 ushorts = 16 KiB
#define REGION(BUF, MAT, KH) (lds + ((((BUF) << 2) | ((MAT) << 1) | (KH)) << 13))

// Stage one half-tile (256 rows x 32 k) of matrix MAT for K-tile KT into REGION(BUF,MAT,KH).
// 2 x global_load_lds(16B) per wave; dest wave-uniform, HW adds lane*16 (linear).
#define STAGE(BUF, MAT, KH, KT)                                               \
  {                                                                           \
    const unsigned short* g_ =                                                \
        ((MAT) == 0 ? Aps : Bps) + (size_t)(KT) * 64 + (KH) * 32;             \
    unsigned short* l_ = REGION(BUF, MAT, KH) + wofs;                         \
    gld_lds16((const void*)g_, (void*)l_);                                    \
    gld_lds16((const void*)(g_ + rstep), (void*)(l_ + 4096));                 \
  }

// One phase: quadrant (MH half of wave's 128 rows) x k-slice KS of buffer BUF.
// B fragments are (re)loaded on MH==0 phases and reused on MH==1.
#define PHASE(BUF, KS, MH, STAGE_CODE, DO_VM)                                 \
  {                                                                           \
    if ((MH) == 0) {                                                          \
      const unsigned short* rb_ = REGION(BUF, 1, KS);                         \
      bq[0] = *(const bf16x8*)(rb_ + boff[0]);                                \
      bq[1] = *(const bf16x8*)(rb_ + boff[1]);                                \
      bq[2] = *(const bf16x8*)(rb_ + boff[2]);                                \
      bq[3] = *(const bf16x8*)(rb_ + boff[3]);                                \
    }                                                                         \
    {                                                                         \
      const unsigned short* ra_ = REGION(BUF, 0, KS);                         \
      aq[0] = *(const bf16x8*)(ra_ + aoff[MH][0]);                            \
      aq[1] = *(const bf16x8*)(ra_ + aoff[MH][1]);                            \
      aq[2] = *(const bf16x8*)(ra_ + aoff[MH][2]);                            \
      aq[3] = *(const bf16x8*)(ra_ + aoff[MH][3]);                            \
    }                                                                         \
    STAGE_CODE;                                                               \
    BARRIER();                                                                \
    WAIT_LGKM0();                                                             \
    __builtin_amdgcn_sched_barrier(0);                                        \
    __builtin_amdgcn_s_setprio(1);                                            \
    _Pragma("unroll")                                                         \
    for (int j = 0; j < 4; ++j) {                                             \
      _Pragma("unroll")                                                       \
      for (int n = 0; n < 4; ++n) {                                           \
        acc[(MH) * 4 + j][n] = __builtin_amdgcn_mfma_f32_16x16x32_bf16(       \
            aq[j], bq[n], acc[(MH) * 4 + j][n], 0, 0, 0);                     \
      }                                                                       \
    }                                                                         \
    __builtin_amdgcn_s_setprio(0);                                            \
    if (DO_VM) { WAIT_VM6(); }                                                \
    BARRIER();                                                                \
  }

__global__ __launch_bounds__(512, 2) void gemm_kernel(
    const unsigned short* __restrict__ A,   // x bf16 [M,K]
    const unsigned short* __restrict__ B,   // w bf16 [N,K]
    const float* __restrict__ bias,         // [N]
    float* __restrict__ C) {                // [M,N] fp32
  extern __shared__ unsigned short lds[];

  const int tid  = threadIdx.x;
  const int lane = tid & 63;
  const int w    = tid >> 6;   // wave 0..7
  const int wm   = w >> 2;     // 0..1 (M half)
  const int wn   = w & 3;      // 0..3 (N quarter)

  // Bijective XCD-aware block swizzle: 1376 blocks = 8 XCDs x 172.
  // Consecutive remapped blocks share the same A-panel (n-fastest decompose).
  int flat = blockIdx.y * gridDim.x + blockIdx.x;       // 0..1375
  flat = (flat & 7) * 172 + (flat >> 3);
  const int bn = (flat % 43) * 256;
  const int bm = (flat / 43) * 256;

  // ---- read-side lane constants (swizzled) ----
  const int fr  = lane & 15;                                   // row-in-frag
  const int kxu = ((lane >> 4) * 8) ^ (((fr >> 1) & 3) << 3);  // ushort k-offset, swizzle folded in
  int aoff[2][4], boff[4];
#pragma unroll
  for (int mh = 0; mh < 2; ++mh)
#pragma unroll
    for (int j = 0; j < 4; ++j)
      aoff[mh][j] = (wm * 128 + mh * 64 + j * 16 + fr) * 32 + kxu;
#pragma unroll
  for (int n = 0; n < 4; ++n)
    boff[n] = (wn * 64 + n * 16 + fr) * 32 + kxu;

  // ---- stage-side lane constants (pre-swizzled global source) ----
  const int sl   = lane ^ ((lane >> 3) & 3);   // same involution as the read swizzle
  const int skol = (sl & 3) * 8;
  const unsigned short* Aps = A + (size_t)(bm + w * 16 + (sl >> 2)) * K_DIM + skol;
  const unsigned short* Bps = B + (size_t)(bn + w * 16 + (sl >> 2)) * K_DIM + skol;
  const size_t rstep = (size_t)128 * K_DIM;    // +128 global rows (part 1 of half-tile)
  const int wofs = w * 512;                    // wave's linear slice in a region (ushorts)

  f32x4 acc[8][4] = {};
  bf16x8 aq[4], bq[4];

  // Prologue: K-tile 0 fully into buf0, first 3 half-tiles of K-tile 1 into buf1.
  // 14 loads issued; vmcnt(6) retires the 8 oldest = all of buf0.
  STAGE(0, 1, 0, 0); STAGE(0, 0, 0, 0); STAGE(0, 1, 1, 0); STAGE(0, 0, 1, 0);
  STAGE(1, 1, 0, 1); STAGE(1, 0, 0, 1); STAGE(1, 1, 1, 1);
  WAIT_VM6();
  BARRIER();

  // Main loop: iteration i computes K-tiles 2i (buf0, ph0-3) and 2i+1 (buf1, ph4-7).
  // Staging ledger (each region overwritten exactly one barrier after its last reader):
  //   ph0: buf1 A-kh1 (kt 2i+1)   ph4: buf0 A-kh1 (kt 2i+2)
  //   ph1: buf0 B-kh0 (kt 2i+2)   ph5: buf1 B-kh0 (kt 2i+3)
  //   ph2: buf0 A-kh0 (kt 2i+2)   ph6: buf1 A-kh0 (kt 2i+3)
  //   ph3: buf0 B-kh1 (kt 2i+2)   ph7: buf1 B-kh1 (kt 2i+3)
  // vmcnt(6) at ph3 retires {ph5,6,7(prev), ph0} = all of buf1 before ph4 reads;
  // vmcnt(6) at ph7 retires {ph1,2,3,4} = all of buf0 before next ph0 reads.
  // Final iteration: kt2/kt3 clamp to 63 (harmless re-stage, keeps vmcnt counts identical).
#pragma unroll 1
  for (int i = 0; i < NITER; ++i) {
    const int kt1 = 2 * i + 1;
    const int kt2 = (2 * i + 2 < K_TILES) ? (2 * i + 2) : (K_TILES - 1);
    const int kt3 = (2 * i + 3 < K_TILES) ? (2 * i + 3) : (K_TILES - 1);
    PHASE(0, 0, 0, STAGE(1, 0, 1, kt1), 0);
    PHASE(0, 0, 1, STAGE(0, 1, 0, kt2), 0);
    PHASE(0, 1, 0, STAGE(0, 0, 0, kt2), 0);
    PHASE(0, 1, 1, STAGE(0, 1, 1, kt2), 1);
    PHASE(1, 0, 0, STAGE(0, 0, 1, kt2), 0);
    PHASE(1, 0, 1, STAGE(1, 1, 0, kt3), 0);
    PHASE(1, 1, 0, STAGE(1, 0, 0, kt3), 0);
    PHASE(1, 1, 1, STAGE(1, 1, 1, kt3), 1);
  }

  // Epilogue: C/D layout col=lane&15, row=(lane>>4)*4+reg (m89/m91-verified)
  const int orow = bm + wm * 128 + (lane >> 4) * 4;
  const int ocol = bn + wn * 64 + fr;
  float bv[4];
#pragma unroll
  for (int n = 0; n < 4; ++n) bv[n] = bias[ocol + n * 16];
#pragma unroll
  for (int mi = 0; mi < 8; ++mi) {
    const int r0 = orow + (mi >> 2) * 64 + (mi & 3) * 16;
#pragma unroll
    for (int n = 0; n < 4; ++n) {
#pragma unroll
      for (int r = 0; r < 4; ++r) {
        C[(size_t)(r0 + r) * N_DIM + (ocol + n * 16)] = acc[mi][n][r] + bv[n];
      }
    }
  }
}

extern "C" void kernel_launch(void* const* d_in, const int* in_sizes, int n_in,
                              void* d_out, int out_size, void* d_ws, size_t ws_size,
                              hipStream_t stream) {
  const float* x      = (const float*)d_in[0];  // [4,2048,4096] fp32
  const int*   wq     = (const int*)d_in[1];    // [11008,2048] int32
  const float* scales = (const float*)d_in[2];  // [11008,64]
  const float* zeros  = (const float*)d_in[3];  // [11008,64]
  const float* csc    = (const float*)d_in[4];  // [4096]
  const float* bias   = (const float*)d_in[5];  // [11008]
  float* out = (float*)d_out;                   // [4,2048,11008] fp32

  // Workspace layout: xb (67,108,864 B) then wb (90,177,536 B) = 150 MiB
  unsigned short* xb = (unsigned short*)d_ws;
  unsigned short* wb = (unsigned short*)((char*)d_ws + (size_t)M_DIM * K_DIM * 2);

  cvt_x_kernel<<<16384, 256, 0, stream>>>(x, xb);
  dequant_w_kernel<<<22016, 256, 0, stream>>>(wq, scales, zeros, csc, wb);

  static bool attr_set = false;
  if (!attr_set) {
    hipFuncSetAttribute(reinterpret_cast<const void*>(gemm_kernel),
                        hipFuncAttributeMaxDynamicSharedMemorySize, 131072);
    attr_set = true;
  }
  dim3 grid(N_DIM / 256, M_DIM / 256);  // 43 x 32 = 1376 blocks, 1 block/CU (128 KiB LDS)
  gemm_kernel<<<grid, 512, 131072, stream>>>(xb, wb, bias, out);
}